// Round 20
// baseline (260.018 us; speedup 1.0000x reference)
//
#include <hip/hip_runtime.h>
#include <stdint.h>

typedef unsigned short u16;
typedef __attribute__((ext_vector_type(4))) float f32x4;
typedef __attribute__((ext_vector_type(16))) float f32x16;
typedef __attribute__((ext_vector_type(8))) short bf16x8;
typedef __attribute__((ext_vector_type(4))) unsigned short u16x4;
typedef __attribute__((ext_vector_type(4))) unsigned u32x4;

static __device__ __forceinline__ u16 f2bf(float f) {
  union { float f; unsigned u; } v; v.f = f;
  unsigned r = v.u + 0x7fffu + ((v.u >> 16) & 1u);
  return (u16)(r >> 16);
}
static __device__ __forceinline__ float bf2f(u16 u) {
  union { unsigned u; float f; } v; v.u = ((unsigned)u) << 16;
  return v.f;
}

static __device__ __forceinline__ unsigned cvtpk(float lo, float hi) {
  unsigned r;
  asm("v_cvt_pk_bf16_f32 %0, %1, %2" : "=v"(r) : "v"(lo), "v"(hi));
  return r;
}

static __device__ __forceinline__ void plane32_swap(unsigned& a, unsigned& b) {
  asm volatile("v_permlane32_swap_b32 %0, %1" : "+v"(a), "+v"(b));
}

static __device__ __forceinline__ float exp2_fast(float x) {
  float r;
  asm("v_exp_f32 %0, %1" : "=v"(r) : "v"(x));
  return r;
}

static __device__ __forceinline__ void load_lds16(const void* g, void* l) {
  __builtin_amdgcn_global_load_lds(
      (const __attribute__((address_space(1))) void*)g,
      (__attribute__((address_space(3))) void*)l, 16, 0, 0);
}

// ---------------- fused conversions: x->bf16, [Wq;Wk;Wv]->wcat, Wo->bf16 --------------
__global__ __launch_bounds__(256) void cvt_all(
    const float* __restrict__ x, const float* __restrict__ Wq,
    const float* __restrict__ Wk, const float* __restrict__ Wv,
    const float* __restrict__ Wo, u16* __restrict__ xb,
    u16* __restrict__ wcat, u16* __restrict__ wob) {
  int i = blockIdx.x * 256 + threadIdx.x;
  const int nx = 2097152, nw = 1572864, total = 4718592;  // 4-elem chunks
  for (; i < total; i += gridDim.x * 256) {
    const float* src;
    u16* dst;
    if (i < nx) {
      src = x + (size_t)i * 4;
      dst = xb + (size_t)i * 4;
    } else if (i < nx + nw) {
      int k = i - nx;
      int row = k >> 9, c4 = k & 511;
      const float* s;
      if (row < 2048)      s = Wq + (size_t)row * 2048;
      else if (row < 2560) s = Wk + (size_t)(row - 2048) * 2048;
      else                 s = Wv + (size_t)(row - 2560) * 2048;
      src = s + c4 * 4;
      dst = wcat + (size_t)k * 4;
    } else {
      int k = i - nx - nw;
      src = Wo + (size_t)k * 4;
      dst = wob + (size_t)k * 4;
    }
    f32x4 v = *(const f32x4*)src;
    u16x4 o = { f2bf(v[0]), f2bf(v[1]), f2bf(v[2]), f2bf(v[3]) };
    *(u16x4*)dst = o;
  }
}

// ======== BK=64 32x32x16 GEMM core (shared by both GEMMs) =========================
#define GEMM_CORE(C_STORE)                                                            \
  __shared__ u16 As[128 * 64];                                                        \
  __shared__ u16 Bs[128 * 64];                                                        \
  const int tid = threadIdx.x;                                                        \
  const int lin = blockIdx.x;                                                         \
  const int x = lin & 7, t = lin >> 3; /* bid%8 == XCD */                             \
  const int bm = x * 4 + (t & 3);                                                     \
  const int bn = t >> 2;                                                              \
  const int w = tid >> 6, l = tid & 63;                                               \
  const int wr = w >> 1, wc = w & 1;                                                  \
  const int ql = l & 31, hi = l >> 5;                                                 \
  f32x16 acc[2][2] = {};                                                              \
  const int nk = K >> 6;                                                              \
  for (int kt = 0; kt < nk; ++kt) {                                                   \
    __syncthreads();                                                                  \
    const int ko = kt << 6;                                                           \
    _Pragma("unroll")                                                                 \
    for (int j = 0; j < 4; ++j) {                                                     \
      int idx = j * 256 + tid;                                                        \
      int row = idx >> 3, ch = idx & 7;                                               \
      int col = ko + (((ch ^ (row & 7))) << 3);                                       \
      load_lds16(A + (size_t)(bm * 128 + row) * K + col, As + idx * 8);               \
      load_lds16(B + (size_t)(bn * 128 + row) * K + col, Bs + idx * 8);               \
    }                                                                                 \
    __syncthreads();                                                                  \
    _Pragma("unroll")                                                                 \
    for (int ks = 0; ks < 4; ++ks) {                                                  \
      const int e = ks * 2 + hi;                                                      \
      bf16x8 af[2], bfr[2];                                                           \
      _Pragma("unroll")                                                               \
      for (int ti = 0; ti < 2; ++ti) {                                                \
        const int ra = wr * 64 + ti * 32 + ql;                                        \
        const int rb = wc * 64 + ti * 32 + ql;                                        \
        af[ti]  = *(const bf16x8*)&As[ra * 64 + ((e ^ (ra & 7)) << 3)];               \
        bfr[ti] = *(const bf16x8*)&Bs[rb * 64 + ((e ^ (rb & 7)) << 3)];               \
      }                                                                               \
      _Pragma("unroll")                                                               \
      for (int mi = 0; mi < 2; ++mi)                                                  \
        _Pragma("unroll")                                                             \
        for (int ni = 0; ni < 2; ++ni)                                                \
          acc[mi][ni] = __builtin_amdgcn_mfma_f32_32x32x16_bf16(                      \
              af[mi], bfr[ni], acc[mi][ni], 0, 0, 0);                                 \
    }                                                                                 \
  }                                                                                   \
  _Pragma("unroll")                                                                   \
  for (int mi = 0; mi < 2; ++mi) {                                                    \
    const int rb0 = bm * 128 + wr * 64 + mi * 32;                                     \
    _Pragma("unroll")                                                                 \
    for (int ni = 0; ni < 2; ++ni) {                                                  \
      const int col = bn * 128 + wc * 64 + ni * 32 + ql;                              \
      _Pragma("unroll")                                                               \
      for (int r = 0; r < 16; ++r) {                                                  \
        const int row = rb0 + (r & 3) + 8 * (r >> 2) + 4 * hi;                        \
        C_STORE;                                                                      \
      }                                                                               \
    }                                                                                 \
  }

__global__ __launch_bounds__(256) void gemm_bt16(
    const u16* __restrict__ A, const u16* __restrict__ B,
    u16* __restrict__ C, int M, int N, int K) {
  GEMM_CORE(C[(size_t)row * N + col] = f2bf(acc[mi][ni][r]))
}

__global__ __launch_bounds__(256) void gemm_bt(
    const u16* __restrict__ A, const u16* __restrict__ B,
    float* __restrict__ C, int M, int N, int K) {
  GEMM_CORE(C[(size_t)row * N + col] = acc[mi][ni][r])
}

// ---------------- per-head RMSNorm + RoPE (bf16 input; q scaled by 1/(sqrt(128)ln2)) --
__global__ __launch_bounds__(256) void norm_rope(
    const u16* __restrict__ qkv, const float* __restrict__ qn_w,
    const float* __restrict__ kn_w, const float* __restrict__ cosb,
    const float* __restrict__ sinb, u16* __restrict__ qhat,
    u16* __restrict__ khat) {
  const int gw = (blockIdx.x * 256 + threadIdx.x) >> 6;
  const int lane = threadIdx.x & 63;
  const int slot = gw % 20;
  const int row = gw / 20;  // b*2048 + t
  const int t = row & 2047;
  const int b = row >> 11;
  const u16* src; const float* nw; u16* dst;
  bool isq = slot < 16;
  if (isq) {
    src = qkv + (size_t)row * 3072 + slot * 128;
    nw = qn_w;
    dst = qhat + ((size_t)(b * 16 + slot) * 2048 + t) * 128;
  } else {
    src = qkv + (size_t)row * 3072 + 2048 + (slot - 16) * 128;
    nw = kn_w;
    dst = khat + ((size_t)(b * 4 + (slot - 16)) * 2048 + t) * 128;
  }
  float x1 = bf2f(src[lane]), x2 = bf2f(src[lane + 64]);
  float ss = x1 * x1 + x2 * x2;
#pragma unroll
  for (int o = 32; o; o >>= 1) ss += __shfl_xor(ss, o);
  float rs = rsqrtf(ss * (1.0f / 128.0f) + 1e-6f);
  float h1 = x1 * rs * nw[lane];
  float h2 = x2 * rs * nw[lane + 64];
  float c = cosb[t * 128 + lane], s = sinb[t * 128 + lane];
  float o1 = h1 * c - h2 * s;
  float o2 = h2 * c + h1 * s;
  if (isq) { o1 *= 0.12751744752f; o2 *= 0.12751744752f; }  // 1/(sqrt(128)*ln2)
  dst[lane] = f2bf(o1);
  dst[lane + 64] = f2bf(o2);
}

// ---------------- V transpose: qkv bf16 [.,3072] v-cols -> vT bf16 [B,KV,D,T] ---------
__global__ __launch_bounds__(256) void v_trans(
    const u16* __restrict__ qkv, u16* __restrict__ vT) {
  __shared__ u16 st[64][130];
  const int bi = blockIdx.x;
  const int tt = bi & 31;
  const int kv = (bi >> 5) & 3;
  const int b = bi >> 7;
  const int tid = threadIdx.x;
#pragma unroll
  for (int i = 0; i < 32; ++i) {
    int idx = i * 256 + tid;
    int t = idx >> 7, d = idx & 127;
    st[t][d] = qkv[(size_t)(b * 2048 + tt * 64 + t) * 3072 + 2560 + kv * 128 + d];
  }
  __syncthreads();
#pragma unroll
  for (int i = 0; i < 32; ++i) {
    int idx = i * 256 + tid;
    int d = idx >> 6, t = idx & 63;
    vT[((size_t)(b * 4 + kv) * 128 + d) * 2048 + tt * 64 + t] = st[t][d];
  }
}

// ---------------- causal GQA flash attention (4-warp, V single-buffer, 3 blocks/CU) ---
// R15 algorithm with Vt single-buffered: LDS 48KB -> 3 blocks/CU (12 waves/CU vs 8).
// Cost: 2nd barrier/tile to publish V(t) (staged after barrier-1, vmcnt-drained at
// barrier-2 just before PV). PV(t-1) reads finish before barrier-1(t) -> WAR safe.
// Both barriers unconditional (causal skip gates compute only). K prefetch overlaps
// QK^T+softmax (force-drained at barrier-2, still ahead of its use next tile).
__global__ __launch_bounds__(256, 3) void attn(
    const u16* __restrict__ qhat, const u16* __restrict__ khat,
    const u16* __restrict__ vT, u16* __restrict__ yb) {
  __shared__ u16 Kt[2][64 * 128];   // 32 KB
  __shared__ u16 Vt[128 * 64];      // 16 KB (single buffer)
  const int bi = blockIdx.x;        // [0,512)
  const int j = bi & 255;
  const int pairup = bi >> 8;
  const int bh = j >> 3;            // b*16 + h
  const int cc = j & 7;
  const int c = pairup ? (15 - cc) : cc;   // this block's 128-row strip
  const int h = bh & 15, b = bh >> 4;
  const int kvh = h >> 2;
  const int tid = threadIdx.x;
  const int w = tid >> 6, l = tid & 63;
  const int ql = l & 31, hi = l >> 5;
  const int wq0 = c * 128 + w * 32;
  const int wq_end = wq0 + 31;
  const int qg = wq0 + ql;

  bf16x8 qf[8];
  const u16* qp = qhat + ((size_t)(b * 16 + h) * 2048 + qg) * 128 + hi * 8;
#pragma unroll
  for (int sf = 0; sf < 8; ++sf) qf[sf] = *(const bf16x8*)(qp + 16 * sf);

  f32x16 yacc[4] = {};
  float m = -1e30f, lsum = 0.f;

  const u16* Kg = khat + (size_t)(b * 4 + kvh) * 2048 * 128;
  const u16* Vg = vT + (size_t)(b * 4 + kvh) * 128 * 2048;
  const int nt = 2 * c + 2;         // tiles covering kv <= (c+1)*128

  auto stageK = [&](int tile, int buf) {
#pragma unroll
    for (int jj = 0; jj < 4; ++jj) {
      int idx = jj * 256 + tid;
      int row = idx >> 4, ch = idx & 15;
      load_lds16(Kg + (size_t)(tile * 64 + row) * 128 + ((ch ^ (row & 7)) * 8),
                 &Kt[buf][idx * 8]);
    }
  };
  auto stageV = [&](int tile) {
#pragma unroll
    for (int jj = 0; jj < 4; ++jj) {
      int idx = jj * 256 + tid;
      int row = idx >> 3, ch = idx & 7;
      load_lds16(Vg + (size_t)row * 2048 + tile * 64 + ((ch ^ (row & 7)) * 8),
                 &Vt[idx * 8]);
    }
  };

  stageK(0, 0);
  int cur = 0;
  for (int tile = 0; tile < nt; ++tile) {
    const int kv0 = tile * 64;
    __syncthreads();  // barrier-1: Kt[cur] ready; Vt free (prev PV reads complete)
    if (tile + 1 < nt) stageK(tile + 1, cur ^ 1);
    stageV(tile);
    const bool act = (kv0 <= wq_end);
    bf16x8 pa[4];
    if (act) {
      const u16* Kc = Kt[cur];
      f32x16 sacc[2] = {};
      __builtin_amdgcn_s_setprio(1);
#pragma unroll
      for (int n = 0; n < 2; ++n) {
#pragma unroll
        for (int sf = 0; sf < 8; ++sf) {
          bf16x8 kf = *(const bf16x8*)&Kc[(n * 32 + ql) * 128 + (((2 * sf + hi) ^ (l & 7)) * 8)];
          sacc[n] = __builtin_amdgcn_mfma_f32_32x32x16_bf16(kf, qf[sf], sacc[n], 0, 0, 0);
        }
      }
      __builtin_amdgcn_s_setprio(0);
      if (kv0 + 63 > wq0) {
#pragma unroll
        for (int n = 0; n < 2; ++n)
#pragma unroll
          for (int r = 0; r < 16; ++r) {
            int kv = kv0 + n * 32 + (r & 3) + 8 * (r >> 2) + 4 * hi;
            if (kv > qg) sacc[n][r] = -1e30f;
          }
      }
      float pm = -1e30f;
#pragma unroll
      for (int n = 0; n < 2; ++n)
#pragma unroll
        for (int r = 0; r < 16; ++r) pm = fmaxf(pm, sacc[n][r]);
      pm = fmaxf(pm, __shfl_xor(pm, 32));
      if (!__all(pm - m <= 11.0f)) {  // defer-max, log2 units (P <= 2^11)
        float mn = fmaxf(m, pm);
        float sc = exp2_fast(m - mn);
        m = mn;
        lsum *= sc;
#pragma unroll
        for (int r = 0; r < 16; ++r) {
          int row = (r & 3) + 8 * (r >> 2) + 4 * hi;
          float scr = __shfl(sc, row);
#pragma unroll
          for (int d = 0; d < 4; ++d) yacc[d][r] *= scr;
        }
      }
      float ls = 0.f;
#pragma unroll
      for (int n = 0; n < 2; ++n)
#pragma unroll
        for (int r = 0; r < 16; ++r) {
          float e = exp2_fast(sacc[n][r] - m);
          sacc[n][r] = e;
          ls += e;
        }
      ls += __shfl_xor(ls, 32);
      lsum += ls;
#pragma unroll
      for (int s4 = 0; s4 < 4; ++s4) {
        const int n = s4 >> 1, R = (s4 & 1) * 8;
        unsigned P01 = cvtpk(sacc[n][R + 0], sacc[n][R + 1]);
        unsigned P23 = cvtpk(sacc[n][R + 2], sacc[n][R + 3]);
        unsigned P45 = cvtpk(sacc[n][R + 4], sacc[n][R + 5]);
        unsigned P67 = cvtpk(sacc[n][R + 6], sacc[n][R + 7]);
        plane32_swap(P01, P45);
        plane32_swap(P23, P67);
        union { u32x4 u; bf16x8 bv; } cvu;
        cvu.u[0] = P01; cvu.u[1] = P23; cvu.u[2] = P45; cvu.u[3] = P67;
        pa[s4] = cvu.bv;
      }
    }
    __syncthreads();  // barrier-2: Vt staged (vmcnt drained) and visible
    if (act) {
      __builtin_amdgcn_s_setprio(1);
#pragma unroll
      for (int d = 0; d < 4; ++d) {
        const int rv = d * 32 + ql;
#pragma unroll
        for (int ks = 0; ks < 4; ++ks) {
          bf16x8 vf = *(const bf16x8*)&Vt[rv * 64 + (((ks * 2 + hi) ^ (rv & 7)) * 8)];
          yacc[d] = __builtin_amdgcn_mfma_f32_32x32x16_bf16(pa[ks], vf, yacc[d], 0, 0, 0);
        }
      }
      __builtin_amdgcn_s_setprio(0);
    }
    cur ^= 1;
  }
#pragma unroll
  for (int r = 0; r < 16; ++r) {
    int row = (r & 3) + 8 * (r >> 2) + 4 * hi;
    float li = __shfl(lsum, row);
    float inv = 1.0f / li;
    u16* yp = yb + ((size_t)(b * 2048) + wq0 + row) * 2048 + h * 128 + ql;
#pragma unroll
    for (int d = 0; d < 4; ++d) yp[d * 32] = f2bf(yacc[d][r] * inv);
  }
}

// ---------------- launcher ----------------

extern "C" void kernel_launch(void* const* d_in, const int* in_sizes, int n_in,
                              void* d_out, int out_size, void* d_ws, size_t ws_size,
                              hipStream_t stream) {
  const float* x    = (const float*)d_in[0];
  const float* Wq   = (const float*)d_in[1];
  const float* Wk   = (const float*)d_in[2];
  const float* Wv   = (const float*)d_in[3];
  const float* Wo   = (const float*)d_in[4];
  const float* qn   = (const float*)d_in[5];
  const float* kn   = (const float*)d_in[6];
  const float* cosb = (const float*)d_in[7];
  const float* sinb = (const float*)d_in[8];
  float* out = (float*)d_out;
  (void)in_sizes; (void)n_in; (void)out_size; (void)ws_size;

  char* p = (char*)d_ws;
  u16*   xb   = (u16*)p;   p += (size_t)8388608 * 2;    // x bf16 [4096,2048]
  u16*   wcat = (u16*)p;   p += (size_t)6291456 * 2;    // [3072,2048]
  u16*   wob  = (u16*)p;   p += (size_t)4194304 * 2;    // [2048,2048]
  u16*   qkvb = (u16*)p;   p += (size_t)12582912 * 2;   // [4096,3072] bf16
  u16*   qh   = (u16*)p;   p += (size_t)8388608 * 2;    // [2,16,2048,128]
  u16*   kh   = (u16*)p;   p += (size_t)2097152 * 2;    // [2,4,2048,128]
  u16*   vt   = (u16*)p;   p += (size_t)2097152 * 2;    // [2,4,128,2048]
  u16*   yb   = (u16*)p;   p += (size_t)8388608 * 2;    // [4096,2048]

  cvt_all<<<2048, 256, 0, stream>>>(x, Wq, Wk, Wv, Wo, xb, wcat, wob);
  gemm_bt16<<<768, 256, 0, stream>>>(xb, wcat, qkvb, 4096, 3072, 2048);
  norm_rope<<<20480, 256, 0, stream>>>(qkvb, qn, kn, cosb, sinb, qh, kh);
  v_trans<<<256, 256, 0, stream>>>(qkvb, vt);
  attn<<<512, 256, 0, stream>>>(qh, kh, vt, yb);
  gemm_bt<<<512, 256, 0, stream>>>(yb, wob, out, 4096, 2048, 2048);
}

// Round 21
// 208.565 us; speedup vs baseline: 1.2467x; 1.2467x over previous
//
#include <hip/hip_runtime.h>
#include <stdint.h>

typedef unsigned short u16;
typedef __attribute__((ext_vector_type(4))) float f32x4;
typedef __attribute__((ext_vector_type(16))) float f32x16;
typedef __attribute__((ext_vector_type(8))) short bf16x8;
typedef __attribute__((ext_vector_type(4))) unsigned short u16x4;
typedef __attribute__((ext_vector_type(4))) unsigned u32x4;

static __device__ __forceinline__ u16 f2bf(float f) {
  union { float f; unsigned u; } v; v.f = f;
  unsigned r = v.u + 0x7fffu + ((v.u >> 16) & 1u);
  return (u16)(r >> 16);
}
static __device__ __forceinline__ float bf2f(u16 u) {
  union { unsigned u; float f; } v; v.u = ((unsigned)u) << 16;
  return v.f;
}

static __device__ __forceinline__ unsigned cvtpk(float lo, float hi) {
  unsigned r;
  asm("v_cvt_pk_bf16_f32 %0, %1, %2" : "=v"(r) : "v"(lo), "v"(hi));
  return r;
}

static __device__ __forceinline__ void plane32_swap(unsigned& a, unsigned& b) {
  asm volatile("v_permlane32_swap_b32 %0, %1" : "+v"(a), "+v"(b));
}

static __device__ __forceinline__ float exp2_fast(float x) {
  float r;
  asm("v_exp_f32 %0, %1" : "=v"(r) : "v"(x));
  return r;
}

static __device__ __forceinline__ void load_lds16(const void* g, void* l) {
  __builtin_amdgcn_global_load_lds(
      (const __attribute__((address_space(1))) void*)g,
      (__attribute__((address_space(3))) void*)l, 16, 0, 0);
}

// ---------------- fused conversions: x->bf16, [Wq;Wk;Wv]->wcat, Wo->bf16 --------------
__global__ __launch_bounds__(256) void cvt_all(
    const float* __restrict__ x, const float* __restrict__ Wq,
    const float* __restrict__ Wk, const float* __restrict__ Wv,
    const float* __restrict__ Wo, u16* __restrict__ xb,
    u16* __restrict__ wcat, u16* __restrict__ wob) {
  int i = blockIdx.x * 256 + threadIdx.x;
  const int nx = 2097152, nw = 1572864, total = 4718592;  // 4-elem chunks
  for (; i < total; i += gridDim.x * 256) {
    const float* src;
    u16* dst;
    if (i < nx) {
      src = x + (size_t)i * 4;
      dst = xb + (size_t)i * 4;
    } else if (i < nx + nw) {
      int k = i - nx;
      int row = k >> 9, c4 = k & 511;
      const float* s;
      if (row < 2048)      s = Wq + (size_t)row * 2048;
      else if (row < 2560) s = Wk + (size_t)(row - 2048) * 2048;
      else                 s = Wv + (size_t)(row - 2560) * 2048;
      src = s + c4 * 4;
      dst = wcat + (size_t)k * 4;
    } else {
      int k = i - nx - nw;
      src = Wo + (size_t)k * 4;
      dst = wob + (size_t)k * 4;
    }
    f32x4 v = *(const f32x4*)src;
    u16x4 o = { f2bf(v[0]), f2bf(v[1]), f2bf(v[2]), f2bf(v[3]) };
    *(u16x4*)dst = o;
  }
}

// ======== BK=64 32x32x16 GEMM core (shared by both GEMMs) =========================
#define GEMM_CORE(C_STORE)                                                            \
  __shared__ u16 As[128 * 64];                                                        \
  __shared__ u16 Bs[128 * 64];                                                        \
  const int tid = threadIdx.x;                                                        \
  const int lin = blockIdx.x;                                                         \
  const int x = lin & 7, t = lin >> 3; /* bid%8 == XCD */                             \
  const int bm = x * 4 + (t & 3);                                                     \
  const int bn = t >> 2;                                                              \
  const int w = tid >> 6, l = tid & 63;                                               \
  const int wr = w >> 1, wc = w & 1;                                                  \
  const int ql = l & 31, hi = l >> 5;                                                 \
  f32x16 acc[2][2] = {};                                                              \
  const int nk = K >> 6;                                                              \
  for (int kt = 0; kt < nk; ++kt) {                                                   \
    __syncthreads();                                                                  \
    const int ko = kt << 6;                                                           \
    _Pragma("unroll")                                                                 \
    for (int j = 0; j < 4; ++j) {                                                     \
      int idx = j * 256 + tid;                                                        \
      int row = idx >> 3, ch = idx & 7;                                               \
      int col = ko + (((ch ^ (row & 7))) << 3);                                       \
      load_lds16(A + (size_t)(bm * 128 + row) * K + col, As + idx * 8);               \
      load_lds16(B + (size_t)(bn * 128 + row) * K + col, Bs + idx * 8);               \
    }                                                                                 \
    __syncthreads();                                                                  \
    _Pragma("unroll")                                                                 \
    for (int ks = 0; ks < 4; ++ks) {                                                  \
      const int e = ks * 2 + hi;                                                      \
      bf16x8 af[2], bfr[2];                                                           \
      _Pragma("unroll")                                                               \
      for (int ti = 0; ti < 2; ++ti) {                                                \
        const int ra = wr * 64 + ti * 32 + ql;                                        \
        const int rb = wc * 64 + ti * 32 + ql;                                        \
        af[ti]  = *(const bf16x8*)&As[ra * 64 + ((e ^ (ra & 7)) << 3)];               \
        bfr[ti] = *(const bf16x8*)&Bs[rb * 64 + ((e ^ (rb & 7)) << 3)];               \
      }                                                                               \
      _Pragma("unroll")                                                               \
      for (int mi = 0; mi < 2; ++mi)                                                  \
        _Pragma("unroll")                                                             \
        for (int ni = 0; ni < 2; ++ni)                                                \
          acc[mi][ni] = __builtin_amdgcn_mfma_f32_32x32x16_bf16(                      \
              af[mi], bfr[ni], acc[mi][ni], 0, 0, 0);                                 \
    }                                                                                 \
  }                                                                                   \
  _Pragma("unroll")                                                                   \
  for (int mi = 0; mi < 2; ++mi) {                                                    \
    const int rb0 = bm * 128 + wr * 64 + mi * 32;                                     \
    _Pragma("unroll")                                                                 \
    for (int ni = 0; ni < 2; ++ni) {                                                  \
      const int col = bn * 128 + wc * 64 + ni * 32 + ql;                              \
      _Pragma("unroll")                                                               \
      for (int r = 0; r < 16; ++r) {                                                  \
        const int row = rb0 + (r & 3) + 8 * (r >> 2) + 4 * hi;                        \
        C_STORE;                                                                      \
      }                                                                               \
    }                                                                                 \
  }

__global__ __launch_bounds__(256) void gemm_bt16(
    const u16* __restrict__ A, const u16* __restrict__ B,
    u16* __restrict__ C, int M, int N, int K) {
  GEMM_CORE(C[(size_t)row * N + col] = f2bf(acc[mi][ni][r]))
}

__global__ __launch_bounds__(256) void gemm_bt(
    const u16* __restrict__ A, const u16* __restrict__ B,
    float* __restrict__ C, int M, int N, int K) {
  GEMM_CORE(C[(size_t)row * N + col] = acc[mi][ni][r])
}

// ---------------- per-head RMSNorm + RoPE (bf16 input; q scaled by 1/(sqrt(128)ln2)) --
__global__ __launch_bounds__(256) void norm_rope(
    const u16* __restrict__ qkv, const float* __restrict__ qn_w,
    const float* __restrict__ kn_w, const float* __restrict__ cosb,
    const float* __restrict__ sinb, u16* __restrict__ qhat,
    u16* __restrict__ khat) {
  const int gw = (blockIdx.x * 256 + threadIdx.x) >> 6;
  const int lane = threadIdx.x & 63;
  const int slot = gw % 20;
  const int row = gw / 20;  // b*2048 + t
  const int t = row & 2047;
  const int b = row >> 11;
  const u16* src; const float* nw; u16* dst;
  bool isq = slot < 16;
  if (isq) {
    src = qkv + (size_t)row * 3072 + slot * 128;
    nw = qn_w;
    dst = qhat + ((size_t)(b * 16 + slot) * 2048 + t) * 128;
  } else {
    src = qkv + (size_t)row * 3072 + 2048 + (slot - 16) * 128;
    nw = kn_w;
    dst = khat + ((size_t)(b * 4 + (slot - 16)) * 2048 + t) * 128;
  }
  float x1 = bf2f(src[lane]), x2 = bf2f(src[lane + 64]);
  float ss = x1 * x1 + x2 * x2;
#pragma unroll
  for (int o = 32; o; o >>= 1) ss += __shfl_xor(ss, o);
  float rs = rsqrtf(ss * (1.0f / 128.0f) + 1e-6f);
  float h1 = x1 * rs * nw[lane];
  float h2 = x2 * rs * nw[lane + 64];
  float c = cosb[t * 128 + lane], s = sinb[t * 128 + lane];
  float o1 = h1 * c - h2 * s;
  float o2 = h2 * c + h1 * s;
  if (isq) { o1 *= 0.12751744752f; o2 *= 0.12751744752f; }  // 1/(sqrt(128)*ln2)
  dst[lane] = f2bf(o1);
  dst[lane + 64] = f2bf(o2);
}

// ---------------- V transpose: qkv bf16 [.,3072] v-cols -> vT bf16 [B,KV,D,T] ---------
__global__ __launch_bounds__(256) void v_trans(
    const u16* __restrict__ qkv, u16* __restrict__ vT) {
  __shared__ u16 st[64][130];
  const int bi = blockIdx.x;
  const int tt = bi & 31;
  const int kv = (bi >> 5) & 3;
  const int b = bi >> 7;
  const int tid = threadIdx.x;
#pragma unroll
  for (int i = 0; i < 32; ++i) {
    int idx = i * 256 + tid;
    int t = idx >> 7, d = idx & 127;
    st[t][d] = qkv[(size_t)(b * 2048 + tt * 64 + t) * 3072 + 2560 + kv * 128 + d];
  }
  __syncthreads();
#pragma unroll
  for (int i = 0; i < 32; ++i) {
    int idx = i * 256 + tid;
    int d = idx >> 6, t = idx & 63;
    vT[((size_t)(b * 4 + kv) * 128 + d) * 2048 + tt * 64 + t] = st[t][d];
  }
}

// ---------------- causal GQA flash attention (R15 verified: 4-warp, 2 blocks/CU) ------
// 512 blocks x 4 warps, one 128-row strip per block; blocks bi and bi+256 carry strips
// cc and 15-cc of the same (b,h) (uniform 34-tile pairs, shared K/V in L2), phase-skewed
// on one CU. K+V LDS dbuf, swapped 32x32 QK^T, in-register log2 softmax.
__global__ __launch_bounds__(256, 2) void attn(
    const u16* __restrict__ qhat, const u16* __restrict__ khat,
    const u16* __restrict__ vT, u16* __restrict__ yb) {
  __shared__ u16 Kt[2][64 * 128];   // 32 KB
  __shared__ u16 Vt[2][128 * 64];   // 32 KB
  const int bi = blockIdx.x;        // [0,512)
  const int j = bi & 255;
  const int pairup = bi >> 8;
  const int bh = j >> 3;            // b*16 + h
  const int cc = j & 7;
  const int c = pairup ? (15 - cc) : cc;   // this block's 128-row strip
  const int h = bh & 15, b = bh >> 4;
  const int kvh = h >> 2;
  const int tid = threadIdx.x;
  const int w = tid >> 6, l = tid & 63;
  const int ql = l & 31, hi = l >> 5;
  const int wq0 = c * 128 + w * 32;
  const int wq_end = wq0 + 31;
  const int qg = wq0 + ql;

  bf16x8 qf[8];
  const u16* qp = qhat + ((size_t)(b * 16 + h) * 2048 + qg) * 128 + hi * 8;
#pragma unroll
  for (int sf = 0; sf < 8; ++sf) qf[sf] = *(const bf16x8*)(qp + 16 * sf);

  f32x16 yacc[4] = {};
  float m = -1e30f, lsum = 0.f;

  const u16* Kg = khat + (size_t)(b * 4 + kvh) * 2048 * 128;
  const u16* Vg = vT + (size_t)(b * 4 + kvh) * 128 * 2048;
  const int nt = 2 * c + 2;         // tiles covering kv <= (c+1)*128

  auto stageK = [&](int tile, int buf) {
#pragma unroll
    for (int jj = 0; jj < 4; ++jj) {
      int idx = jj * 256 + tid;
      int row = idx >> 4, ch = idx & 15;
      load_lds16(Kg + (size_t)(tile * 64 + row) * 128 + ((ch ^ (row & 7)) * 8),
                 &Kt[buf][idx * 8]);
    }
  };
  auto stageV = [&](int tile, int buf) {
#pragma unroll
    for (int jj = 0; jj < 4; ++jj) {
      int idx = jj * 256 + tid;
      int row = idx >> 3, ch = idx & 7;
      load_lds16(Vg + (size_t)row * 2048 + tile * 64 + ((ch ^ (row & 7)) * 8),
                 &Vt[buf][idx * 8]);
    }
  };

  stageK(0, 0);
  stageV(0, 0);
  int cur = 0;
  for (int tile = 0; tile < nt; ++tile) {
    const int kv0 = tile * 64;
    __syncthreads();
    if (tile + 1 < nt) { stageK(tile + 1, cur ^ 1); stageV(tile + 1, cur ^ 1); }
    if (kv0 <= wq_end) {
      const u16* Kc = Kt[cur];
      const u16* Vc = Vt[cur];
      f32x16 sacc[2] = {};
      __builtin_amdgcn_s_setprio(1);
#pragma unroll
      for (int n = 0; n < 2; ++n) {
#pragma unroll
        for (int sf = 0; sf < 8; ++sf) {
          bf16x8 kf = *(const bf16x8*)&Kc[(n * 32 + ql) * 128 + (((2 * sf + hi) ^ (l & 7)) * 8)];
          sacc[n] = __builtin_amdgcn_mfma_f32_32x32x16_bf16(kf, qf[sf], sacc[n], 0, 0, 0);
        }
      }
      __builtin_amdgcn_s_setprio(0);
      if (kv0 + 63 > wq0) {
#pragma unroll
        for (int n = 0; n < 2; ++n)
#pragma unroll
          for (int r = 0; r < 16; ++r) {
            int kv = kv0 + n * 32 + (r & 3) + 8 * (r >> 2) + 4 * hi;
            if (kv > qg) sacc[n][r] = -1e30f;
          }
      }
      float pm = -1e30f;
#pragma unroll
      for (int n = 0; n < 2; ++n)
#pragma unroll
        for (int r = 0; r < 16; ++r) pm = fmaxf(pm, sacc[n][r]);
      pm = fmaxf(pm, __shfl_xor(pm, 32));
      if (!__all(pm - m <= 11.0f)) {  // defer-max, log2 units (P <= 2^11)
        float mn = fmaxf(m, pm);
        float sc = exp2_fast(m - mn);
        m = mn;
        lsum *= sc;
#pragma unroll
        for (int r = 0; r < 16; ++r) {
          int row = (r & 3) + 8 * (r >> 2) + 4 * hi;
          float scr = __shfl(sc, row);
#pragma unroll
          for (int d = 0; d < 4; ++d) yacc[d][r] *= scr;
        }
      }
      float ls = 0.f;
#pragma unroll
      for (int n = 0; n < 2; ++n)
#pragma unroll
        for (int r = 0; r < 16; ++r) {
          float e = exp2_fast(sacc[n][r] - m);
          sacc[n][r] = e;
          ls += e;
        }
      ls += __shfl_xor(ls, 32);
      lsum += ls;
      bf16x8 pa[4];
#pragma unroll
      for (int s4 = 0; s4 < 4; ++s4) {
        const int n = s4 >> 1, R = (s4 & 1) * 8;
        unsigned P01 = cvtpk(sacc[n][R + 0], sacc[n][R + 1]);
        unsigned P23 = cvtpk(sacc[n][R + 2], sacc[n][R + 3]);
        unsigned P45 = cvtpk(sacc[n][R + 4], sacc[n][R + 5]);
        unsigned P67 = cvtpk(sacc[n][R + 6], sacc[n][R + 7]);
        plane32_swap(P01, P45);
        plane32_swap(P23, P67);
        union { u32x4 u; bf16x8 bv; } cvu;
        cvu.u[0] = P01; cvu.u[1] = P23; cvu.u[2] = P45; cvu.u[3] = P67;
        pa[s4] = cvu.bv;
      }
      __builtin_amdgcn_s_setprio(1);
#pragma unroll
      for (int d = 0; d < 4; ++d) {
        const int rv = d * 32 + ql;
#pragma unroll
        for (int ks = 0; ks < 4; ++ks) {
          bf16x8 vf = *(const bf16x8*)&Vc[rv * 64 + (((ks * 2 + hi) ^ (rv & 7)) * 8)];
          yacc[d] = __builtin_amdgcn_mfma_f32_32x32x16_bf16(pa[ks], vf, yacc[d], 0, 0, 0);
        }
      }
      __builtin_amdgcn_s_setprio(0);
    }
    cur ^= 1;
  }
#pragma unroll
  for (int r = 0; r < 16; ++r) {
    int row = (r & 3) + 8 * (r >> 2) + 4 * hi;
    float li = __shfl(lsum, row);
    float inv = 1.0f / li;
    u16* yp = yb + ((size_t)(b * 2048) + wq0 + row) * 2048 + h * 128 + ql;
#pragma unroll
    for (int d = 0; d < 4; ++d) yp[d * 32] = f2bf(yacc[d][r] * inv);
  }
}

// ---------------- launcher ----------------

extern "C" void kernel_launch(void* const* d_in, const int* in_sizes, int n_in,
                              void* d_out, int out_size, void* d_ws, size_t ws_size,
                              hipStream_t stream) {
  const float* x    = (const float*)d_in[0];
  const float* Wq   = (const float*)d_in[1];
  const float* Wk   = (const float*)d_in[2];
  const float* Wv   = (const float*)d_in[3];
  const float* Wo   = (const float*)d_in[4];
  const float* qn   = (const float*)d_in[5];
  const float* kn   = (const float*)d_in[6];
  const float* cosb = (const float*)d_in[7];
  const float* sinb = (const float*)d_in[8];
  float* out = (float*)d_out;
  (void)in_sizes; (void)n_in; (void)out_size; (void)ws_size;

  char* p = (char*)d_ws;
  u16*   xb   = (u16*)p;   p += (size_t)8388608 * 2;    // x bf16 [4096,2048]
  u16*   wcat = (u16*)p;   p += (size_t)6291456 * 2;    // [3072,2048]
  u16*   wob  = (u16*)p;   p += (size_t)4194304 * 2;    // [2048,2048]
  u16*   qkvb = (u16*)p;   p += (size_t)12582912 * 2;   // [4096,3072] bf16
  u16*   qh   = (u16*)p;   p += (size_t)8388608 * 2;    // [2,16,2048,128]
  u16*   kh   = (u16*)p;   p += (size_t)2097152 * 2;    // [2,4,2048,128]
  u16*   vt   = (u16*)p;   p += (size_t)2097152 * 2;    // [2,4,128,2048]
  u16*   yb   = (u16*)p;   p += (size_t)8388608 * 2;    // [4096,2048]

  cvt_all<<<2048, 256, 0, stream>>>(x, Wq, Wk, Wv, Wo, xb, wcat, wob);
  gemm_bt16<<<768, 256, 0, stream>>>(xb, wcat, qkvb, 4096, 3072, 2048);
  norm_rope<<<20480, 256, 0, stream>>>(qkvb, qn, kn, cosb, sinb, qh, kh);
  v_trans<<<256, 256, 0, stream>>>(qkvb, vt);
  attn<<<512, 256, 0, stream>>>(qh, kh, vt, yb);
  gemm_bt<<<512, 256, 0, stream>>>(yb, wob, out, 4096, 2048, 2048);
}